// Round 2
// baseline (77.071 us; speedup 1.0000x reference)
//
#include <hip/hip_runtime.h>

// FastGaussianModel: values[m] = sum_n exp(-0.5 * sum_d (p[m,d]-q[n,d])^2 * iv[n,d]) * w[n]
// Per gaussian: quad' = c' + a.p + b.p^2 with K = -0.5*log2(e) folded in, so
// inner loop = 6 FMA + v_exp_f32 + 1 FMA per pair.
//
// Round 2: coefficients are wave-uniform -> keep them OUT of LDS (LDS return BW
// is per-lane; broadcast reads still cost 8 clk per ds_read_b128). SoA layout +
// uniform indices -> scalar loads (s_load) into SGPRs, folded into VALU srcs.
// float2 ext-vector arithmetic -> v_pk_fma_f32 (double-rate packed fp32).

typedef float v2f __attribute__((ext_vector_type(2)));

constexpr int NG_CHUNK = 128;   // gaussians per block-chunk (grid.y)
constexpr int BLOCK    = 256;   // one point per thread

// --- prep: per-gaussian coefficients, SoA, padded entries -> all-zero (w=0) ---
__global__ void fgm_prep(const float* __restrict__ positions,
                         const float* __restrict__ log_scales,
                         const float* __restrict__ intensities,
                         float* __restrict__ coef, int N, int Npad) {
    int n = blockIdx.x * blockDim.x + threadIdx.x;
    if (n >= Npad) return;
    float a0=0.f, a1=0.f, a2=0.f, b0=0.f, b1=0.f, b2=0.f, c=0.f, w=0.f;
    if (n < N) {
        const float K = -0.7213475204444817f;  // -0.5 * log2(e)
        float q0 = positions[3*n+0], q1 = positions[3*n+1], q2 = positions[3*n+2];
        float iv0 = 1.0f / (__expf(2.0f*log_scales[3*n+0]) + 1e-6f);
        float iv1 = 1.0f / (__expf(2.0f*log_scales[3*n+1]) + 1e-6f);
        float iv2 = 1.0f / (__expf(2.0f*log_scales[3*n+2]) + 1e-6f);
        a0 = K * (-2.f*iv0*q0);  b0 = K * iv0;
        a1 = K * (-2.f*iv1*q1);  b1 = K * iv1;
        a2 = K * (-2.f*iv2*q2);  b2 = K * iv2;
        c  = K * (iv0*q0*q0 + iv1*q1*q1 + iv2*q2*q2);
        w  = intensities[n];
    }
    coef[0*Npad+n] = a0;  coef[1*Npad+n] = a1;  coef[2*Npad+n] = a2;
    coef[3*Npad+n] = b0;  coef[4*Npad+n] = b1;  coef[5*Npad+n] = b2;
    coef[6*Npad+n] = c;   coef[7*Npad+n] = w;
}

// --- main: one point per thread, 2 gaussians per iter (packed fp32) ---
__global__ __launch_bounds__(BLOCK) void fgm_main(const float* __restrict__ points,
                                                  const float* __restrict__ coef,
                                                  float* __restrict__ out,
                                                  int M, int Npad) {
    int m = blockIdx.x * blockDim.x + threadIdx.x;
    float px = 0.f, py = 0.f, pz = 0.f;
    if (m < M) {
        px = points[3*m+0];
        py = points[3*m+1];
        pz = points[3*m+2];
    }
    v2f vpx  = {px, px},       vpy  = {py, py},       vpz  = {pz, pz};
    v2f vpx2 = {px*px, px*px}, vpy2 = {py*py, py*py}, vpz2 = {pz*pz, pz*pz};

    int half = blockIdx.y * (NG_CHUNK/2);  // index into v2f-typed SoA arrays
    const v2f* A0 = (const v2f*)(coef + 0*Npad) + half;
    const v2f* A1 = (const v2f*)(coef + 1*Npad) + half;
    const v2f* A2 = (const v2f*)(coef + 2*Npad) + half;
    const v2f* B0 = (const v2f*)(coef + 3*Npad) + half;
    const v2f* B1 = (const v2f*)(coef + 4*Npad) + half;
    const v2f* B2 = (const v2f*)(coef + 5*Npad) + half;
    const v2f* C  = (const v2f*)(coef + 6*Npad) + half;
    const v2f* W  = (const v2f*)(coef + 7*Npad) + half;

    v2f acc = {0.f, 0.f};
    #pragma unroll 4
    for (int i = 0; i < NG_CHUNK/2; ++i) {
        v2f t = __builtin_elementwise_fma(A0[i], vpx,  C[i]);
        t = __builtin_elementwise_fma(A1[i], vpy,  t);
        t = __builtin_elementwise_fma(A2[i], vpz,  t);
        t = __builtin_elementwise_fma(B0[i], vpx2, t);
        t = __builtin_elementwise_fma(B1[i], vpy2, t);
        t = __builtin_elementwise_fma(B2[i], vpz2, t);
        v2f g;
        g.x = __builtin_amdgcn_exp2f(t.x);
        g.y = __builtin_amdgcn_exp2f(t.y);
        acc = __builtin_elementwise_fma(g, W[i], acc);
    }
    if (m < M) atomicAdd(&out[m], acc.x + acc.y);
}

extern "C" void kernel_launch(void* const* d_in, const int* in_sizes, int n_in,
                              void* d_out, int out_size, void* d_ws, size_t ws_size,
                              hipStream_t stream) {
    const float* points      = (const float*)d_in[0];
    const float* positions   = (const float*)d_in[1];
    const float* log_scales  = (const float*)d_in[2];
    const float* intensities = (const float*)d_in[3];
    int M = in_sizes[0] / 3;
    int N = in_sizes[3];

    int chunks = (N + NG_CHUNK - 1) / NG_CHUNK;
    int Npad   = chunks * NG_CHUNK;

    float* coef = (float*)d_ws;  // 8 * Npad floats, SoA

    // output accumulated via atomics -> zero it (d_out is poisoned 0xAA)
    hipMemsetAsync(d_out, 0, (size_t)out_size * sizeof(float), stream);

    fgm_prep<<<(Npad + 255) / 256, 256, 0, stream>>>(positions, log_scales,
                                                     intensities, coef, N, Npad);

    dim3 grid((M + BLOCK - 1) / BLOCK, chunks);
    fgm_main<<<grid, BLOCK, 0, stream>>>(points, coef, (float*)d_out, M, Npad);
}